// Round 3
// baseline (63193.829 us; speedup 1.0000x reference)
//
#include <hip/hip_runtime.h>
#include <hip/hip_bf16.h>

// ---------------------------------------------------------------------------
// 3-layer LSTM, B=64, T=1024, D=512, H=1024. Persistent kernel, 256 WGs
// (1/CU), output-column partitioning: WG owns 4 hidden cols => 16 z-cols
// (4 gates x 4) with FULL K. Weights [16][K] bf16 in LDS (~64KB). Per step:
//   each wave: z[16m x 16n] = A[16 x K] * W[K x 16] via 16x16x32 bf16 MFMA
//   z -> LDS, local gate pass (c-state in LDS), h -> MALL via agent-scope
//   atomic stores (packed uint).
// SYNC: distributed per-WG flag array; producer drains stores via
// __syncthreads (vmcnt0) then flags[wg]=ev; consumer wave0 polls all 256
// flags. h-state read via agent-scope relaxed atomic b64 loads (MALL-
// coherent, no per-step cache inv). Double-buffered h-state (read t&1,
// write (t&1)^1); skew bounded to 1 event by per-step signaling.
//
// NEW this round (traffic de-amplification -- r2 counters showed 6.9 GB
// HBM vs ~0.9 GB ideal, from partial-line writes):
//  * h-log layout [t][wg][m][4] bf16: producer writes 512 B CONTIGUOUS per
//    step (was 8 B per 2 KB row -> 64 B write-allocate fill + partial-line
//    evict, ~3 GB fetch + ~2 GB write amplification). Consumer reads the
//    step slice as contiguous 128 KB (A-frag = 2 x b64, stride 512 B).
//  * out written by READBACK: phase-2 gate pass publishes fp32 h to
//    hfst[2][64][1024] (512 KB, MALL atomics); after the next rendezvous,
//    WG wg writes out[wg>>2][t-1][(wg&3)*256..+256] = 1 KB contiguous,
//    reading hfst coalesced. Epilogue covers t=1023.
//  * s_sleep(1) in poll loop (cut MALL pressure on the 16 flag lines).
// ---------------------------------------------------------------------------

typedef __attribute__((ext_vector_type(8))) short short8;
typedef __attribute__((ext_vector_type(4))) float f32x4;

#define GRID   256
#define WGS    256
#define TSTEPS 1024
#define HID    1024
#define BATCH  64
#define ZN     4096
#define WTLD   2056              // LDS weight row stride (shorts): 2048 + 8 pad
#define LDS_BYTES 90112          // forces 1 WG/CU; actual use ~71 KB

#define ZL_OFF  65792            // 16*2056*2
#define CS_OFF  (ZL_OFF + 64*17*4)

__device__ __forceinline__ unsigned short f2bf(float f) {
    unsigned u = __float_as_uint(f);
    u += 0x7fffu + ((u >> 16) & 1u);      // round-to-nearest-even
    return (unsigned short)(u >> 16);
}

__device__ __forceinline__ float fast_tanh(float x) {
    x = fminf(15.f, fmaxf(-15.f, x));
    float e = __expf(2.f * x);
    return (e - 1.f) / (e + 1.f);
}

__device__ __forceinline__ float sigm(float x) {
    return 1.f / (1.f + __expf(-x));
}

// Publish event ev for this WG. __syncthreads drains every wave's vmcnt
// (compiler emits s_waitcnt vmcnt(0) before s_barrier), so all h/hfst
// atomic stores are MALL-visible and plain log stores are L2-acked before
// the flag store.
__device__ __forceinline__ void wg_signal(unsigned* flags, int wg, unsigned ev,
                                          bool relfence) {
    __syncthreads();
    if (threadIdx.x == 0) {
        if (relfence)
            __builtin_amdgcn_fence(__ATOMIC_RELEASE, "agent");   // wbl2
        __hip_atomic_store(&flags[wg], ev, __ATOMIC_RELAXED,
                           __HIP_MEMORY_SCOPE_AGENT);
    }
}

// Wait until every WG has published >= ev. Wave 0 polls 4 flags per lane
// (256 total); flags are monotonic so '>= ev' is safe against overrun
// (max skew is 1 event). inv=true additionally invalidates L1+L2 (phase
// boundaries only).
__device__ __forceinline__ void wg_wait(const unsigned* flags, unsigned ev,
                                        bool inv) {
    if (threadIdx.x < 64) {
        const unsigned* fp = flags + (threadIdx.x << 2);
        for (;;) {
            unsigned a = __hip_atomic_load(fp + 0, __ATOMIC_RELAXED, __HIP_MEMORY_SCOPE_AGENT);
            unsigned b = __hip_atomic_load(fp + 1, __ATOMIC_RELAXED, __HIP_MEMORY_SCOPE_AGENT);
            unsigned c = __hip_atomic_load(fp + 2, __ATOMIC_RELAXED, __HIP_MEMORY_SCOPE_AGENT);
            unsigned d = __hip_atomic_load(fp + 3, __ATOMIC_RELAXED, __HIP_MEMORY_SCOPE_AGENT);
            unsigned m0 = a < b ? a : b;
            unsigned m1 = c < d ? c : d;
            unsigned m  = m0 < m1 ? m0 : m1;
            if (__all((int)(m >= ev))) break;
            __builtin_amdgcn_s_sleep(1);
        }
        if (inv)
            __builtin_amdgcn_fence(__ATOMIC_ACQUIRE, "agent");   // inv L1+L2
    }
    __syncthreads();
}

__global__ void initk(unsigned* flags) {
    flags[threadIdx.x] = 0u;
}

__global__ __launch_bounds__(WGS) void lstm3(
    const float* __restrict__ xs,
    const float* __restrict__ Wx0, const float* __restrict__ Wh0, const float* __restrict__ b0,
    const float* __restrict__ Wx1, const float* __restrict__ Wh1, const float* __restrict__ b1,
    const float* __restrict__ Wx2, const float* __restrict__ Wh2, const float* __restrict__ b2,
    float* __restrict__ out,
    unsigned* __restrict__ hst32,        // [2][BATCH][HID/2] packed bf16 pairs (MALL)
    unsigned short* __restrict__ h0buf,  // [TSTEPS][256][64][4] bf16 (layer-0 log)
    unsigned short* __restrict__ h1buf,  // [TSTEPS][256][64][4] bf16 (layer-1 log)
    float* __restrict__ hfst,            // [2][BATCH][HID] fp32 (phase-2 h, MALL)
    unsigned* __restrict__ flags)        // [GRID] per-WG event counters
{
    extern __shared__ unsigned char lds[];
    unsigned short* WT  = (unsigned short*)lds;            // [16][WTLD] k-contiguous
    float*          zl  = (float*)(lds + ZL_OFF);          // [64][17]
    float*          csl = (float*)(lds + CS_OFF);          // [256] cell state

    const int tid  = threadIdx.x;
    const int wg   = blockIdx.x;
    const int wv   = tid >> 6;
    const int lane = tid & 63;
    const int l15  = lane & 15;
    const int quad = lane >> 4;
    const int am   = (wv << 4) + l15;    // this lane's A (batch) row, 0..63
    const int m_g  = tid >> 2;           // gate-pass batch row
    const int hc   = tid & 3;            // gate-pass hidden col within WG's 4
    const int m_o  = wg >> 2;            // out-writer batch row
    const int q_o  = wg & 3;             // out-writer 256-col block
    const unsigned short* hstU = (const unsigned short*)hst32;  // [2][64][1024]

    unsigned ev = 0;

    for (int phase = 0; phase < 3; ++phase) {
        const float* Wx  = phase == 0 ? Wx0 : (phase == 1 ? Wx1 : Wx2);
        const float* Wh  = phase == 0 ? Wh0 : (phase == 1 ? Wh1 : Wh2);
        const float* bia = phase == 0 ? b0  : (phase == 1 ? b1  : b2);
        const unsigned short* xb = phase == 1 ? h0buf : (phase == 2 ? h1buf : (unsigned short*)0);
        unsigned* ho32 = (unsigned*)(phase == 0 ? h0buf : (phase == 1 ? h1buf : (unsigned short*)0));
        const int Kx = (phase == 0) ? 512 : 1024;

        // ---- Round A: previous phase fully drained everywhere; wbl2 publishes
        // its plain log stores; acquire-inv drops our stale copies.
        ++ev; wg_signal(flags, wg, ev, phase > 0);
        wg_wait(flags, ev, true);

        // ---- LDS weight fill: WT[n][k], n -> z-col (gate g = n>>2, col wg*4+(n&3))
        for (int k = tid >> 4; k < Kx + HID; k += 16) {
            int n    = tid & 15;
            int gcol = ((n >> 2) << 10) + (wg << 2) + (n & 3);
            float w  = (k < Kx) ? Wx[(size_t)k * ZN + gcol]
                                : Wh[(size_t)(k - Kx) * ZN + gcol];
            WT[n * WTLD + k] = f2bf(w);
        }
        // ---- zero h-state buffer 0 (the one step 0 reads) + cell state (LDS)
        if (tid < 128)
            __hip_atomic_store(&hst32[(wg << 7) + tid], 0u,
                               __ATOMIC_RELAXED, __HIP_MEMORY_SCOPE_AGENT);
        csl[tid] = 0.f;
        // ---- per-thread bias registers for the gate pass
        const int gc = (wg << 2) + hc;
        float bi_ = bia[gc], bf_ = bia[HID + gc], bg_ = bia[2 * HID + gc], bo_ = bia[3 * HID + gc];

        // ---- Round B: everyone's h-state zeros published before t=0 reads.
        ++ev; wg_signal(flags, wg, ev, false);
        wg_wait(flags, ev, true);

        for (int t = 0; t < TSTEPS; ++t) {
            f32x4 acc0 = {0.f,0.f,0.f,0.f}, acc1 = {0.f,0.f,0.f,0.f};
            f32x4 acc2 = {0.f,0.f,0.f,0.f}, acc3 = {0.f,0.f,0.f,0.f};
            const int ko = quad << 3;    // lane k-offset (8 bf16)

            // ---- x segment (no dependence on h_{t-1}; issued before the wait
            // so it overlaps flag propagation of the previous step)
            if (phase == 0) {
                const float* xr = xs + ((size_t)am * TSTEPS + t) * 512 + ko;
                #pragma unroll 4
                for (int kit = 0; kit < 16; ++kit) {
                    f32x4 lo = *(const f32x4*)(xr + (kit << 5));
                    f32x4 hi = *(const f32x4*)(xr + (kit << 5) + 4);
                    short8 a;
                    #pragma unroll
                    for (int j = 0; j < 4; ++j) {
                        a[j]     = (short)f2bf(lo[j]);
                        a[j + 4] = (short)f2bf(hi[j]);
                    }
                    short8 b = *(const short8*)&WT[l15 * WTLD + (kit << 5) + ko];
                    switch (kit & 3) {
                        case 0: acc0 = __builtin_amdgcn_mfma_f32_16x16x32_bf16(a, b, acc0, 0, 0, 0); break;
                        case 1: acc1 = __builtin_amdgcn_mfma_f32_16x16x32_bf16(a, b, acc1, 0, 0, 0); break;
                        case 2: acc2 = __builtin_amdgcn_mfma_f32_16x16x32_bf16(a, b, acc2, 0, 0, 0); break;
                        default:acc3 = __builtin_amdgcn_mfma_f32_16x16x32_bf16(a, b, acc3, 0, 0, 0); break;
                    }
                }
            } else {
                // log layout [t][ws=256][m=64][c=4] shorts: addr =
                // t*65536 + ws*256 + am*4 + c; lane's 8 k's span ws0, ws0+1
                const unsigned short* xr = xb + ((size_t)t << 16) + (am << 2);
                #pragma unroll 8
                for (int kit = 0; kit < 32; ++kit) {
                    const int ws0 = (kit << 3) + (quad << 1);   // (kit*32+quad*8)>>2
                    union { unsigned long long u[2]; short8 s; } ua;
                    ua.u[0] = *(const unsigned long long*)(xr + (ws0 << 8));
                    ua.u[1] = *(const unsigned long long*)(xr + (ws0 << 8) + 256);
                    short8 a = ua.s;
                    short8 b = *(const short8*)&WT[l15 * WTLD + (kit << 5) + ko];
                    switch (kit & 3) {
                        case 0: acc0 = __builtin_amdgcn_mfma_f32_16x16x32_bf16(a, b, acc0, 0, 0, 0); break;
                        case 1: acc1 = __builtin_amdgcn_mfma_f32_16x16x32_bf16(a, b, acc1, 0, 0, 0); break;
                        case 2: acc2 = __builtin_amdgcn_mfma_f32_16x16x32_bf16(a, b, acc2, 0, 0, 0); break;
                        default:acc3 = __builtin_amdgcn_mfma_f32_16x16x32_bf16(a, b, acc3, 0, 0, 0); break;
                    }
                }
            }

            // ---- wait: all WGs have published h_{t-1} (flags >= ev)
            wg_wait(flags, ev, false);

            // ---- out writeback (phase 2): h_{t-1} now globally visible in
            // hfst[t&1]; WG wg writes out[wg>>2][t-1][q*256..+256], 1 KB
            // contiguous (full lines -- no partial-line RMW).
            if (phase == 2 && t > 0) {
                float hv = __hip_atomic_load(
                    &hfst[((t & 1) << 16) + (m_o << 10) + (q_o << 8) + tid],
                    __ATOMIC_RELAXED, __HIP_MEMORY_SCOPE_AGENT);
                out[((size_t)m_o * TSTEPS + (t - 1)) * HID + (q_o << 8) + tid] = hv;
            }

            // ---- h segment (recurrent), K = 1024, from buffer t&1 via
            // agent-scope atomic b64 loads (MALL-coherent, no inv needed).
            // k-stride: one kit = 32 bf16 = 64 B = 8 ull (hence kit<<3).
            {
                const unsigned long long* hr = (const unsigned long long*)
                    (hstU + ((size_t)(t & 1) << 16) + ((size_t)am << 10) + ko);
                #pragma unroll 8
                for (int kit = 0; kit < 32; ++kit) {
                    union { unsigned long long u[2]; short8 s; } ua;
                    ua.u[0] = __hip_atomic_load(hr + (kit << 3) + 0,
                                                __ATOMIC_RELAXED, __HIP_MEMORY_SCOPE_AGENT);
                    ua.u[1] = __hip_atomic_load(hr + (kit << 3) + 1,
                                                __ATOMIC_RELAXED, __HIP_MEMORY_SCOPE_AGENT);
                    short8 a = ua.s;
                    short8 b = *(const short8*)&WT[l15 * WTLD + Kx + (kit << 5) + ko];
                    switch (kit & 3) {
                        case 0: acc0 = __builtin_amdgcn_mfma_f32_16x16x32_bf16(a, b, acc0, 0, 0, 0); break;
                        case 1: acc1 = __builtin_amdgcn_mfma_f32_16x16x32_bf16(a, b, acc1, 0, 0, 0); break;
                        case 2: acc2 = __builtin_amdgcn_mfma_f32_16x16x32_bf16(a, b, acc2, 0, 0, 0); break;
                        default:acc3 = __builtin_amdgcn_mfma_f32_16x16x32_bf16(a, b, acc3, 0, 0, 0); break;
                    }
                }
            }
            f32x4 z4 = (acc0 + acc1) + (acc2 + acc3);
            // D-frag: row m = quad*4 + r (within wave's 16), col n = l15
            #pragma unroll
            for (int r = 0; r < 4; ++r)
                zl[((wv << 4) + (quad << 2) + r) * 17 + l15] = z4[r];
            // No __syncthreads here: gate rows m_g = tid>>2 lie inside this
            // wave's own 16 rows; LDS ops are in-order within a wave.

            // ---- gate pass: thread = (m_g, hc); z-cols g*4+hc, g = 0..3
            {
                float zi = zl[m_g * 17 + hc]      + bi_;
                float zf = zl[m_g * 17 + 4 + hc]  + bf_;
                float zg = zl[m_g * 17 + 8 + hc]  + bg_;
                float zo = zl[m_g * 17 + 12 + hc] + bo_;
                float ig = sigm(zi), fg = sigm(zf);
                float gg = fast_tanh(zg), og = sigm(zo);
                float c  = fg * csl[tid] + ig * gg;
                csl[tid] = c;
                float h  = og * fast_tanh(c);
                const int wbuf = (t & 1) ^ 1;

                if (phase == 2)
                    __hip_atomic_store(&hfst[(wbuf << 16) + (m_g << 10) + gc], h,
                                       __ATOMIC_RELAXED, __HIP_MEMORY_SCOPE_AGENT);

                unsigned hb = (unsigned)f2bf(h);
                unsigned ob = (unsigned)__shfl_xor((int)hb, 1);
                if ((tid & 1) == 0) {
                    unsigned packed = hb | (ob << 16);
                    __hip_atomic_store(&hst32[(wbuf << 15) + (m_g << 9) + (wg << 1) + (hc >> 1)],
                                       packed, __ATOMIC_RELAXED, __HIP_MEMORY_SCOPE_AGENT);
                    // contiguous 512 B/WG log write: [t][wg][m][4] (uint units)
                    if (phase < 2)
                        ho32[((size_t)t << 15) + (wg << 7) + (m_g << 1) + (hc >> 1)] = packed;
                }
            }
            // ---- publish h_t (syncthreads inside drains all waves' stores)
            ++ev;
            wg_signal(flags, wg, ev, false);
        }

        // ---- phase-2 epilogue: flush the last step's out rows (t=1023,
        // stored to hfst buffer 0 at t=1023 since wbuf=(1023&1)^1=0)
        if (phase == 2) {
            wg_wait(flags, ev, false);
            float hv = __hip_atomic_load(&hfst[(m_o << 10) + (q_o << 8) + tid],
                                         __ATOMIC_RELAXED, __HIP_MEMORY_SCOPE_AGENT);
            out[((size_t)m_o * TSTEPS + (TSTEPS - 1)) * HID + (q_o << 8) + tid] = hv;
        }
    }
}

extern "C" void kernel_launch(void* const* d_in, const int* in_sizes, int n_in,
                              void* d_out, int out_size, void* d_ws, size_t ws_size,
                              hipStream_t stream) {
    const float* xs  = (const float*)d_in[0];
    const float* Wx0 = (const float*)d_in[1];
    const float* Wh0 = (const float*)d_in[2];
    const float* b0  = (const float*)d_in[3];
    const float* Wx1 = (const float*)d_in[4];
    const float* Wh1 = (const float*)d_in[5];
    const float* b1  = (const float*)d_in[6];
    const float* Wx2 = (const float*)d_in[7];
    const float* Wh2 = (const float*)d_in[8];
    const float* b2  = (const float*)d_in[9];

    unsigned char* w = (unsigned char*)d_ws;
    unsigned* flags  = (unsigned*)w;       w += 1024;                                 // 256 flags
    unsigned* hst32  = (unsigned*)w;       w += (size_t)2 * BATCH * (HID / 2) * 4;    // 256 KB (dbuf)
    unsigned short* h0 = (unsigned short*)w; w += (size_t)TSTEPS * 256 * 64 * 4 * 2;  // 128 MB
    unsigned short* h1 = (unsigned short*)w; w += (size_t)TSTEPS * 256 * 64 * 4 * 2;  // 128 MB
    float* hfst      = (float*)w;          w += (size_t)2 * BATCH * HID * 4;          // 512 KB

    (void)hipFuncSetAttribute((const void*)lstm3,
                              hipFuncAttributeMaxDynamicSharedMemorySize, LDS_BYTES);

    initk<<<1, GRID, 0, stream>>>(flags);
    lstm3<<<GRID, WGS, LDS_BYTES, stream>>>(
        xs, Wx0, Wh0, b0, Wx1, Wh1, b1, Wx2, Wh2, b2,
        (float*)d_out, hst32, h0, h1, hfst, flags);
}

// Round 5
// 35984.189 us; speedup vs baseline: 1.7562x; 1.7562x over previous
//
#include <hip/hip_runtime.h>
#include <hip/hip_bf16.h>

// ---------------------------------------------------------------------------
// 3-layer LSTM, B=64, T=1024, D=512, H=1024. Persistent kernel, 256 WGs
// (1/CU), output-column partitioning: WG owns 4 hidden cols => 16 z-cols
// (4 gates x 4) with FULL K. Weights [16][K] bf16 in LDS (~64KB). Per step:
//   each wave: z[16m x 16n] = A[16 x K] * W[K x 16] via 16x16x32 bf16 MFMA
//   z -> LDS, local gate pass (c-state in LDS), h -> MALL via agent-scope
//   atomic stores (packed uint).
// SYNC: distributed per-WG flag array; producer drains stores via
// __syncthreads (vmcnt0) then flags[wg]=ev; consumer wave0 polls all 256
// flags. h-state read via agent-scope relaxed atomic b64 loads (MALL-
// coherent, no per-step cache inv). Double-buffered h-state (read t&1,
// write (t&1)^1); skew bounded to 1 event: a WG writes buffer (t&1)^1 only
// after wait(ev_{t-1}) which proves every WG signaled step t-1, and the
// signal sits AFTER that WG's reads of the same buffer.
//
// r4 (resubmit -- r4 bench was an infra failure, no data): latency-chain
// fix. r0/r2/r3 all stuck ~15-20us/step with every pipe idle; diagnosis:
// compiler held a 48-VGPR budget so the 64 h-loads/step were consumed
// through a 2-4-deep window = ~16 serialized fabric RTTs ~= 8-10us/step.
//  * __launch_bounds__(256,1): LDS already forces 1 WG/CU, so VGPRs are
//    free to 256/wave -- use them as memory-level parallelism.
//  * h segment: ALL 32 kit fragments batch-loaded into hv[32] (128 VGPR,
//    static unroll) back-to-back, then 32 MFMAs. One RTT instead of ~16.
//  * x segment (ph1/2 xv[32], ph0 f32x4 pairs): same batching; sits before
//    the flag wait so L2/HBM latency overlaps the rendezvous.
//  * r3's out-readback/hfst and s_sleep reverted (r3 post-mortem: added
//    serial fabric hops, +5us/step). out written directly (r2 style).
//  * r3's contiguous log layout [t][wg][64][4] kept (512 B/WG/step writes).
//  * log/out stores moved AFTER the flag signal (drain at next barrier,
//    off the critical path).
// ---------------------------------------------------------------------------

typedef __attribute__((ext_vector_type(8))) short short8;
typedef __attribute__((ext_vector_type(4))) float f32x4;

#define GRID   256
#define WGS    256
#define TSTEPS 1024
#define HID    1024
#define BATCH  64
#define ZN     4096
#define WTLD   2056              // LDS weight row stride (shorts): 2048 + 8 pad
#define LDS_BYTES 90112          // forces 1 WG/CU; actual use ~71 KB

#define ZL_OFF  65792            // 16*2056*2
#define CS_OFF  (ZL_OFF + 64*17*4)

__device__ __forceinline__ unsigned short f2bf(float f) {
    unsigned u = __float_as_uint(f);
    u += 0x7fffu + ((u >> 16) & 1u);      // round-to-nearest-even
    return (unsigned short)(u >> 16);
}

__device__ __forceinline__ float fast_tanh(float x) {
    x = fminf(15.f, fmaxf(-15.f, x));
    float e = __expf(2.f * x);
    return (e - 1.f) / (e + 1.f);
}

__device__ __forceinline__ float sigm(float x) {
    return 1.f / (1.f + __expf(-x));
}

// Publish event ev for this WG. __syncthreads drains every wave's vmcnt
// (compiler emits s_waitcnt vmcnt(0) before s_barrier), so all h atomic
// stores are MALL-visible and prior plain stores are L2-acked before the
// flag store.
__device__ __forceinline__ void wg_signal(unsigned* flags, int wg, unsigned ev,
                                          bool relfence) {
    __syncthreads();
    if (threadIdx.x == 0) {
        if (relfence)
            __builtin_amdgcn_fence(__ATOMIC_RELEASE, "agent");   // wbl2
        __hip_atomic_store(&flags[wg], ev, __ATOMIC_RELAXED,
                           __HIP_MEMORY_SCOPE_AGENT);
    }
}

// Wait until every WG has published >= ev. Wave 0 polls 4 flags per lane
// (256 total); flags are monotonic so '>= ev' is safe against overrun
// (max skew is 1 event). inv=true additionally invalidates L1+L2 (phase
// boundaries only).
__device__ __forceinline__ void wg_wait(const unsigned* flags, unsigned ev,
                                        bool inv) {
    if (threadIdx.x < 64) {
        const unsigned* fp = flags + (threadIdx.x << 2);
        for (;;) {
            unsigned a = __hip_atomic_load(fp + 0, __ATOMIC_RELAXED, __HIP_MEMORY_SCOPE_AGENT);
            unsigned b = __hip_atomic_load(fp + 1, __ATOMIC_RELAXED, __HIP_MEMORY_SCOPE_AGENT);
            unsigned c = __hip_atomic_load(fp + 2, __ATOMIC_RELAXED, __HIP_MEMORY_SCOPE_AGENT);
            unsigned d = __hip_atomic_load(fp + 3, __ATOMIC_RELAXED, __HIP_MEMORY_SCOPE_AGENT);
            unsigned m0 = a < b ? a : b;
            unsigned m1 = c < d ? c : d;
            unsigned m  = m0 < m1 ? m0 : m1;
            if (__all((int)(m >= ev))) break;
        }
        if (inv)
            __builtin_amdgcn_fence(__ATOMIC_ACQUIRE, "agent");   // inv L1+L2
    }
    __syncthreads();
}

__global__ void initk(unsigned* flags) {
    flags[threadIdx.x] = 0u;
}

__global__ __launch_bounds__(WGS, 1) void lstm3(
    const float* __restrict__ xs,
    const float* __restrict__ Wx0, const float* __restrict__ Wh0, const float* __restrict__ b0,
    const float* __restrict__ Wx1, const float* __restrict__ Wh1, const float* __restrict__ b1,
    const float* __restrict__ Wx2, const float* __restrict__ Wh2, const float* __restrict__ b2,
    float* __restrict__ out,
    unsigned* __restrict__ hst32,        // [2][BATCH][HID/2] packed bf16 pairs (MALL)
    unsigned short* __restrict__ h0buf,  // [TSTEPS][256][64][4] bf16 (layer-0 log)
    unsigned short* __restrict__ h1buf,  // [TSTEPS][256][64][4] bf16 (layer-1 log)
    unsigned* __restrict__ flags)        // [GRID] per-WG event counters
{
    extern __shared__ unsigned char lds[];
    unsigned short* WT  = (unsigned short*)lds;            // [16][WTLD] k-contiguous
    float*          zl  = (float*)(lds + ZL_OFF);          // [64][17]
    float*          csl = (float*)(lds + CS_OFF);          // [256] cell state

    const int tid  = threadIdx.x;
    const int wg   = blockIdx.x;
    const int wv   = tid >> 6;
    const int lane = tid & 63;
    const int l15  = lane & 15;
    const int quad = lane >> 4;
    const int am   = (wv << 4) + l15;    // this lane's A (batch) row, 0..63
    const int m_g  = tid >> 2;           // gate-pass batch row
    const int hc   = tid & 3;            // gate-pass hidden col within WG's 4
    const unsigned short* hstU = (const unsigned short*)hst32;  // [2][64][1024]

    unsigned ev = 0;

    for (int phase = 0; phase < 3; ++phase) {
        const float* Wx  = phase == 0 ? Wx0 : (phase == 1 ? Wx1 : Wx2);
        const float* Wh  = phase == 0 ? Wh0 : (phase == 1 ? Wh1 : Wh2);
        const float* bia = phase == 0 ? b0  : (phase == 1 ? b1  : b2);
        const unsigned short* xb = phase == 1 ? h0buf : (phase == 2 ? h1buf : (unsigned short*)0);
        unsigned* ho32 = (unsigned*)(phase == 0 ? h0buf : (phase == 1 ? h1buf : (unsigned short*)0));
        const int Kx = (phase == 0) ? 512 : 1024;

        // ---- Round A: previous phase fully drained everywhere; wbl2 publishes
        // its plain log stores; acquire-inv drops our stale copies.
        ++ev; wg_signal(flags, wg, ev, phase > 0);
        wg_wait(flags, ev, true);

        // ---- LDS weight fill: WT[n][k], n -> z-col (gate g = n>>2, col wg*4+(n&3))
        for (int k = tid >> 4; k < Kx + HID; k += 16) {
            int n    = tid & 15;
            int gcol = ((n >> 2) << 10) + (wg << 2) + (n & 3);
            float w  = (k < Kx) ? Wx[(size_t)k * ZN + gcol]
                                : Wh[(size_t)(k - Kx) * ZN + gcol];
            WT[n * WTLD + k] = f2bf(w);
        }
        // ---- zero h-state buffer 0 (the one step 0 reads) + cell state (LDS)
        if (tid < 128)
            __hip_atomic_store(&hst32[(wg << 7) + tid], 0u,
                               __ATOMIC_RELAXED, __HIP_MEMORY_SCOPE_AGENT);
        csl[tid] = 0.f;
        // ---- per-thread bias registers for the gate pass
        const int gc = (wg << 2) + hc;
        float bi_ = bia[gc], bf_ = bia[HID + gc], bg_ = bia[2 * HID + gc], bo_ = bia[3 * HID + gc];

        // ---- Round B: everyone's h-state zeros published before t=0 reads.
        ++ev; wg_signal(flags, wg, ev, false);
        wg_wait(flags, ev, true);

        for (int t = 0; t < TSTEPS; ++t) {
            f32x4 acc0 = {0.f,0.f,0.f,0.f}, acc1 = {0.f,0.f,0.f,0.f};
            f32x4 acc2 = {0.f,0.f,0.f,0.f}, acc3 = {0.f,0.f,0.f,0.f};
            const int ko = quad << 3;    // lane k-offset (8 bf16)

            // ---- x segment (no dependence on h_{t-1}; issued before the wait
            // so the loads overlap flag propagation of the previous step).
            // Batched: all loads issued back-to-back, then all MFMAs.
            if (phase == 0) {
                const float* xr = xs + ((size_t)am * TSTEPS + t) * 512 + ko;
                f32x4 xlo[16], xhi[16];
                #pragma unroll
                for (int kit = 0; kit < 16; ++kit) {
                    xlo[kit] = *(const f32x4*)(xr + (kit << 5));
                    xhi[kit] = *(const f32x4*)(xr + (kit << 5) + 4);
                }
                #pragma unroll
                for (int kit = 0; kit < 16; ++kit) {
                    short8 a;
                    #pragma unroll
                    for (int j = 0; j < 4; ++j) {
                        a[j]     = (short)f2bf(xlo[kit][j]);
                        a[j + 4] = (short)f2bf(xhi[kit][j]);
                    }
                    short8 b = *(const short8*)&WT[l15 * WTLD + (kit << 5) + ko];
                    switch (kit & 3) {
                        case 0: acc0 = __builtin_amdgcn_mfma_f32_16x16x32_bf16(a, b, acc0, 0, 0, 0); break;
                        case 1: acc1 = __builtin_amdgcn_mfma_f32_16x16x32_bf16(a, b, acc1, 0, 0, 0); break;
                        case 2: acc2 = __builtin_amdgcn_mfma_f32_16x16x32_bf16(a, b, acc2, 0, 0, 0); break;
                        default:acc3 = __builtin_amdgcn_mfma_f32_16x16x32_bf16(a, b, acc3, 0, 0, 0); break;
                    }
                }
            } else {
                // log layout [t][ws=256][m=64][c=4] shorts: addr =
                // t*65536 + ws*256 + am*4; lane's 8 k's span ws0, ws0+1
                const unsigned short* xr = xb + ((size_t)t << 16) + (am << 2);
                short8 xv[32];
                #pragma unroll
                for (int kit = 0; kit < 32; ++kit) {
                    const int ws0 = (kit << 3) + (quad << 1);
                    union { unsigned long long u[2]; short8 s; } ua;
                    ua.u[0] = *(const unsigned long long*)(xr + (ws0 << 8));
                    ua.u[1] = *(const unsigned long long*)(xr + (ws0 << 8) + 256);
                    xv[kit] = ua.s;
                }
                #pragma unroll
                for (int kit = 0; kit < 32; ++kit) {
                    short8 b = *(const short8*)&WT[l15 * WTLD + (kit << 5) + ko];
                    switch (kit & 3) {
                        case 0: acc0 = __builtin_amdgcn_mfma_f32_16x16x32_bf16(xv[kit], b, acc0, 0, 0, 0); break;
                        case 1: acc1 = __builtin_amdgcn_mfma_f32_16x16x32_bf16(xv[kit], b, acc1, 0, 0, 0); break;
                        case 2: acc2 = __builtin_amdgcn_mfma_f32_16x16x32_bf16(xv[kit], b, acc2, 0, 0, 0); break;
                        default:acc3 = __builtin_amdgcn_mfma_f32_16x16x32_bf16(xv[kit], b, acc3, 0, 0, 0); break;
                    }
                }
            }

            // ---- wait: all WGs have published h_{t-1} (flags >= ev)
            wg_wait(flags, ev, false);

            // ---- h segment (recurrent), K = 1024, buffer t&1, agent-scope
            // atomic b64 loads (MALL-coherent). ALL 32 fragments batch-loaded
            // first (128 VGPR in flight -> one fabric RTT), then MFMAs.
            {
                const unsigned long long* hr = (const unsigned long long*)
                    (hstU + ((size_t)(t & 1) << 16) + ((size_t)am << 10) + ko);
                short8 hv[32];
                #pragma unroll
                for (int kit = 0; kit < 32; ++kit) {
                    union { unsigned long long u[2]; short8 s; } ua;
                    ua.u[0] = __hip_atomic_load(hr + (kit << 3) + 0,
                                                __ATOMIC_RELAXED, __HIP_MEMORY_SCOPE_AGENT);
                    ua.u[1] = __hip_atomic_load(hr + (kit << 3) + 1,
                                                __ATOMIC_RELAXED, __HIP_MEMORY_SCOPE_AGENT);
                    hv[kit] = ua.s;
                }
                #pragma unroll
                for (int kit = 0; kit < 32; ++kit) {
                    short8 b = *(const short8*)&WT[l15 * WTLD + Kx + (kit << 5) + ko];
                    switch (kit & 3) {
                        case 0: acc0 = __builtin_amdgcn_mfma_f32_16x16x32_bf16(hv[kit], b, acc0, 0, 0, 0); break;
                        case 1: acc1 = __builtin_amdgcn_mfma_f32_16x16x32_bf16(hv[kit], b, acc1, 0, 0, 0); break;
                        case 2: acc2 = __builtin_amdgcn_mfma_f32_16x16x32_bf16(hv[kit], b, acc2, 0, 0, 0); break;
                        default:acc3 = __builtin_amdgcn_mfma_f32_16x16x32_bf16(hv[kit], b, acc3, 0, 0, 0); break;
                    }
                }
            }
            f32x4 z4 = (acc0 + acc1) + (acc2 + acc3);
            // D-frag: row m = quad*4 + r (within wave's 16), col n = l15
            #pragma unroll
            for (int r = 0; r < 4; ++r)
                zl[((wv << 4) + (quad << 2) + r) * 17 + l15] = z4[r];
            // No __syncthreads here: gate rows m_g = tid>>2 lie inside this
            // wave's own 16 rows; LDS ops are in-order within a wave.

            // ---- gate pass: thread = (m_g, hc); z-cols g*4+hc, g = 0..3
            float h;
            unsigned packed = 0;
            {
                float zi = zl[m_g * 17 + hc]      + bi_;
                float zf = zl[m_g * 17 + 4 + hc]  + bf_;
                float zg = zl[m_g * 17 + 8 + hc]  + bg_;
                float zo = zl[m_g * 17 + 12 + hc] + bo_;
                float ig = sigm(zi), fg = sigm(zf);
                float gg = fast_tanh(zg), og = sigm(zo);
                float c  = fg * csl[tid] + ig * gg;
                csl[tid] = c;
                h = og * fast_tanh(c);

                unsigned hb = (unsigned)f2bf(h);
                unsigned ob = (unsigned)__shfl_xor((int)hb, 1);
                if ((tid & 1) == 0) {
                    packed = hb | (ob << 16);
                    const int wbuf = (t & 1) ^ 1;
                    __hip_atomic_store(&hst32[(wbuf << 15) + (m_g << 9) + (wg << 1) + (hc >> 1)],
                                       packed, __ATOMIC_RELAXED, __HIP_MEMORY_SCOPE_AGENT);
                }
            }
            // ---- publish h_t (syncthreads inside drains all waves' stores)
            ++ev;
            wg_signal(flags, wg, ev, false);

            // ---- post-signal stores (off the critical path; drained by the
            // next step's signal barrier / the phase-boundary Round A):
            // contiguous 512 B/WG log write [t][wg][64][4] (uint units)
            if (phase < 2) {
                if ((tid & 1) == 0)
                    ho32[((size_t)t << 15) + (wg << 7) + (m_g << 1) + (hc >> 1)] = packed;
            } else {
                out[((size_t)m_g * TSTEPS + t) * HID + gc] = h;
            }
        }
    }
}

extern "C" void kernel_launch(void* const* d_in, const int* in_sizes, int n_in,
                              void* d_out, int out_size, void* d_ws, size_t ws_size,
                              hipStream_t stream) {
    const float* xs  = (const float*)d_in[0];
    const float* Wx0 = (const float*)d_in[1];
    const float* Wh0 = (const float*)d_in[2];
    const float* b0  = (const float*)d_in[3];
    const float* Wx1 = (const float*)d_in[4];
    const float* Wh1 = (const float*)d_in[5];
    const float* b1  = (const float*)d_in[6];
    const float* Wx2 = (const float*)d_in[7];
    const float* Wh2 = (const float*)d_in[8];
    const float* b2  = (const float*)d_in[9];

    unsigned char* w = (unsigned char*)d_ws;
    unsigned* flags  = (unsigned*)w;       w += 1024;                                 // 256 flags
    unsigned* hst32  = (unsigned*)w;       w += (size_t)2 * BATCH * (HID / 2) * 4;    // 256 KB (dbuf)
    unsigned short* h0 = (unsigned short*)w; w += (size_t)TSTEPS * 256 * 64 * 4 * 2;  // 128 MB
    unsigned short* h1 = (unsigned short*)w; w += (size_t)TSTEPS * 256 * 64 * 4 * 2;  // 128 MB

    (void)hipFuncSetAttribute((const void*)lstm3,
                              hipFuncAttributeMaxDynamicSharedMemorySize, LDS_BYTES);

    initk<<<1, GRID, 0, stream>>>(flags);
    lstm3<<<GRID, WGS, LDS_BYTES, stream>>>(
        xs, Wx0, Wh0, b0, Wx1, Wh1, b1, Wx2, Wh2, b2,
        (float*)d_out, hst32, h0, h1, flags);
}